// Round 1
// 616.114 us; speedup vs baseline: 1.0278x; 1.0278x over previous
//
#include <hip/hip_runtime.h>
#include <hip/hip_bf16.h>
#include <stdint.h>

// Problem dims (fixed)
#define BB 2
#define LL 32
#define EE 256
#define HH 4096
#define GG 16
#define RR 64

typedef __bf16 bf16x8 __attribute__((ext_vector_type(8)));
typedef float f32x4 __attribute__((ext_vector_type(4)));

__device__ inline void async16(const void* g, void* l) {
    __builtin_amdgcn_global_load_lds((const __attribute__((address_space(1))) uint32_t*)g,
                                     (__attribute__((address_space(3))) uint32_t*)l, 16, 0, 0);
}

__device__ inline bf16x8 cvt8(f32x4 a, f32x4 b) {
    bf16x8 r;
    r[0] = (__bf16)a[0]; r[1] = (__bf16)a[1]; r[2] = (__bf16)a[2]; r[3] = (__bf16)a[3];
    r[4] = (__bf16)b[0]; r[5] = (__bf16)b[1]; r[6] = (__bf16)b[2]; r[7] = (__bf16)b[3];
    return r;
}

// ---------------------------------------------------------------------------
// Prep: pre-swizzle Wk/Wv (fp32 [64][4096]) into frag-native bf16 layout:
//   Bfrag[mat][kq(512)][r(64)][j(8)] = W[r][kq*8+j]
// tid ordered so WRITES are fully coalesced (reads scatter into L2 instead).
// Also zero the scores accumulator.
// ---------------------------------------------------------------------------
__global__ __launch_bounds__(256) void prep_kernel(
    const float* __restrict__ Wk, const float* __restrict__ Wv,
    __hip_bfloat16* __restrict__ Bfrag, float* __restrict__ scores)
{
    const int tid = blockIdx.x * 256 + threadIdx.x;   // 65536 tasks
    const int mat = tid >> 15;
    const int kq  = (tid >> 6) & 511;
    const int r   = tid & 63;
    const float* W = mat ? Wv : Wk;
    const float* src = W + (size_t)r * HH + kq * 8;
    f32x4 a = *(const f32x4*)src;
    f32x4 b = *(const f32x4*)(src + 4);
    *(bf16x8*)((__bf16*)Bfrag + (size_t)tid * 8) = cvt8(a, b);   // coalesced 16B store
    if (blockIdx.x == 0 && threadIdx.x < BB * LL) scores[threadIdx.x] = 0.f;
}

// ---------------------------------------------------------------------------
// Proj: kpart[b,l,e,r] = sum_h K[b,l,e,h]*Wk[r,h]  (vpart with Wv), MFMA.
// Counted-vmcnt async pipeline (T3/T4): k-chunk=32, 3 LDS buffers, stage-ahead 2.
// Per iter each wave issues EXACTLY 4 global_load_lds -> branchless vmcnt(4),
// one raw s_barrier per chunk, vmcnt never drained to 0 in the main loop.
// A is XOR-swizzled on the GLOBAL SOURCE address (linear LDS dest) so the
// ds_read_b128 fragment reads are bank-conflict-free.
// Grid 512 = 64 bl x 8 etiles(32 rows). Waves: (mat, mtile). LDS 48 KB.
// Fused: layer-score partial  sum_{e,r} kout*lq[r]  -> atomicAdd(scores[bl]).
// ---------------------------------------------------------------------------
__global__ __launch_bounds__(256, 4) void proj_kernel(
    const float* __restrict__ ek, const float* __restrict__ ev,
    const __hip_bfloat16* __restrict__ Bfrag, const float* __restrict__ lq,
    __hip_bfloat16* __restrict__ kpart, __hip_bfloat16* __restrict__ vpart,
    float* __restrict__ scores)
{
    // LDS: A region 3 bufs x [mat][32 rows][128B, col-swizzled]  = 24576 B
    //      B region 3 bufs x [mat][kq 4][r 64][16B] (frag-native) = 24576 B
    __shared__ __align__(16) uint8_t sm[49152];
    uint8_t* smA = sm;
    uint8_t* smB = sm + 24576;

    const int blk  = blockIdx.x;
    const int bl   = blk >> 3;
    const int e0   = (blk & 7) * 32;
    const int t    = threadIdx.x;
    const int w    = t >> 6;
    const int lane = t & 63;
    const int n    = lane & 15;
    const int q    = lane >> 4;
    const int mat  = w >> 1;    // compute role: 0=K 1=V
    const int mt   = w & 1;     // m-tile (rows mt*16..mt*16+15)

    // staging roles: w0 -> A(ek), w1 -> A(ev), w2 -> B-K, w3 -> B-V
    const int row_l = lane >> 3;                       // 0..7
    const int aswz  = ((lane & 7) ^ row_l) << 4;       // source pre-swizzle
    const char* astage = (const char*)((w & 1) ? ev : ek)
        + ((size_t)(bl * EE + e0 + row_l) * HH) * 4 + aswz;
    const char* bstage = (const char*)Bfrag + ((w & 1) ? (size_t)512 * 1024 : (size_t)0)
        + (size_t)lane * 16;
    uint8_t* adst0 = smA + (w & 1) * 4096;
    uint8_t* bdst0 = smB + (w & 1) * 4096;
    const bool isA = (w < 2);

    auto stage = [&](int cc, int sb) {
        if (isA) {
            const char* g = astage + (size_t)cc * 128;
            uint8_t* d = adst0 + sb * 8192;
#pragma unroll
            for (int p = 0; p < 4; ++p)                 // rows p*8..p*8+7
                async16(g + (size_t)p * (8 * HH * 4), d + p * 1024);
        } else {
            const char* g = bstage + (size_t)cc * 4096;
            uint8_t* d = bdst0 + sb * 8192;
#pragma unroll
            for (int i = 0; i < 4; ++i)                 // kq = cc*4 + i
                async16(g + i * 1024, d + i * 1024);
        }
    };

    f32x4 acc[4] = {};
    const int m = mt * 16 + n;
    const uint8_t* arow0 = smA + mat * 4096 + m * 128;
    const int sA0 = ((2 * q) ^ (n & 7)) << 4;           // swizzled 16B slots
    const int sA1 = ((2 * q + 1) ^ (n & 7)) << 4;
    const uint8_t* brow0 = smB + mat * 4096 + q * 1024 + n * 16;

    // prologue: stage chunks 0,1 (in order -> vmcnt discipline holds)
    stage(0, 0);
    stage(1, 1);

    int cb = 0;                                         // cb = c % 3
    for (int c = 0; c < 128; ++c) {
        // keep chunk c+1's 4 loads in flight; guarantee chunk c landed
        asm volatile("s_waitcnt vmcnt(4)" ::: "memory");
        __builtin_amdgcn_s_barrier();
        asm volatile("" ::: "memory");

        // stage chunk c+2 (wrapped, branchless: tail wraps write dead buffers)
        stage((c + 2) & 127, cb >= 1 ? cb - 1 : 2);     // buf (c+2)%3

        const uint8_t* arow = arow0 + cb * 8192;
        f32x4 a0 = *(const f32x4*)(arow + sA0);
        f32x4 a1 = *(const f32x4*)(arow + sA1);
        bf16x8 af = cvt8(a0, a1);
        const uint8_t* brow = brow0 + cb * 8192;
#pragma unroll
        for (int nt = 0; nt < 4; ++nt) {
            bf16x8 bv = *(const bf16x8*)(brow + nt * 256);
            acc[nt] = __builtin_amdgcn_mfma_f32_16x16x32_bf16(af, bv, acc[nt], 0, 0, 0);
        }
        asm volatile("" ::: "memory");
        cb = (cb == 2) ? 0 : cb + 1;
    }

    // epilogue: store outputs (C/D layout: col=n, row=q*4+reg), fused score
    __hip_bfloat16* outp = (mat == 0) ? kpart : vpart;
    float lqv[4];
    if (mat == 0) {
#pragma unroll
        for (int nt = 0; nt < 4; ++nt) lqv[nt] = lq[nt * 16 + n];
    }
    float sc = 0.f;
#pragma unroll
    for (int nt = 0; nt < 4; ++nt)
#pragma unroll
        for (int reg = 0; reg < 4; ++reg) {
            const int e_row = e0 + mt * 16 + q * 4 + reg;
            outp[((size_t)bl * EE + e_row) * RR + nt * 16 + n] = __float2bfloat16(acc[nt][reg]);
            if (mat == 0) sc += acc[nt][reg] * lqv[nt];
        }
    if (mat == 0) {
#pragma unroll
        for (int off = 32; off > 0; off >>= 1) sc += __shfl_down(sc, off, 64);
        if (lane == 0) atomicAdd(&scores[bl], sc);
    }
    asm volatile("s_waitcnt vmcnt(0)" ::: "memory");    // drain tail stages before exit
}

// ---------------------------------------------------------------------------
// kber: softmax(scores) via wave shuffles; k2[b][e][r] = sum_l w_l*kpart[b,l,e,r]
// (v2 with vpart). Non-transposed fp32 output -> coalesced writes.
// Grid 32 = b(2) x mat(2) x eblk(8 of 32 e). bf16x8 loads = 16B/lane.
// ---------------------------------------------------------------------------
__global__ __launch_bounds__(256) void kber_kernel(
    const __hip_bfloat16* __restrict__ kpart, const __hip_bfloat16* __restrict__ vpart,
    const float* __restrict__ scores,
    float* __restrict__ k2, float* __restrict__ v2)
{
    const int blk = blockIdx.x;
    const int b   = blk >> 4;
    const int mat = (blk >> 3) & 1;
    const int e0  = (blk & 7) * 32;
    const int t = threadIdx.x, w = t >> 6, lane = t & 63;

    // softmax weights, wave-parallel (lanes 32-63 mirror 0-31)
    float sv = scores[b * LL + (lane & 31)] * (1.f / 2048.f);
    float mx = sv;
#pragma unroll
    for (int off = 16; off; off >>= 1) mx = fmaxf(mx, __shfl_xor(mx, off));
    float ex = __expf(sv - mx), sum = ex;
#pragma unroll
    for (int off = 16; off; off >>= 1) sum += __shfl_xor(sum, off);
    const float wgt = ex / sum;          // lane's wl for l = lane&31

    const int e  = e0 + w * 8 + (lane >> 3);
    const int r8 = (lane & 7) * 8;
    const __hip_bfloat16* src = mat ? vpart : kpart;
    const __bf16* base = (const __bf16*)src + ((size_t)b * LL * EE + e) * RR + r8;
    float acc[8] = {};
    for (int l = 0; l < LL; ++l) {
        const float wl = __shfl(wgt, l);
        bf16x8 v8 = *(const bf16x8*)(base + (size_t)l * EE * RR);
#pragma unroll
        for (int j = 0; j < 8; ++j) acc[j] += wl * (float)v8[j];
    }
    float* dst = (mat ? v2 : k2) + ((size_t)b * EE + e) * RR + r8;
    f32x4 o0 = {acc[0], acc[1], acc[2], acc[3]};
    f32x4 o1 = {acc[4], acc[5], acc[6], acc[7]};
    *(f32x4*)dst = o0;
    *(f32x4*)(dst + 4) = o1;
}

// ---------------------------------------------------------------------------
// qproj: q[g,r] = sum_h gq[g,h]*Wq[r,h].  Grid 64 = 16 g x 4 r-quarters.
// ---------------------------------------------------------------------------
__global__ __launch_bounds__(256) void qproj_kernel(
    const float* __restrict__ gq, const float* __restrict__ Wq,
    float* __restrict__ q)
{
    const int g  = blockIdx.x >> 2;
    const int rq = blockIdx.x & 3;
    const int t  = threadIdx.x;
    __shared__ float red[16][256];
    __shared__ float r2[16][17];
    float s[16] = {};
    for (int i = 0; i < 4; i++) {
        const int h = i * 1024 + t * 4;
        f32x4 a = *(const f32x4*)(gq + (size_t)g * HH + h);
#pragma unroll
        for (int r = 0; r < 16; r++) {
            f32x4 wv_ = *(const f32x4*)(Wq + (size_t)(rq * 16 + r) * HH + h);
            s[r] += a[0] * wv_[0] + a[1] * wv_[1] + a[2] * wv_[2] + a[3] * wv_[3];
        }
    }
#pragma unroll
    for (int r = 0; r < 16; r++) red[r][t] = s[r];
    __syncthreads();
    {
        const int r = t >> 4, j = t & 15;
        float p = 0.f;
        for (int i = 0; i < 16; i++) p += red[r][j * 16 + i];
        r2[r][j] = p;
    }
    __syncthreads();
    if (t < 16) {
        float p = 0.f;
        for (int j = 0; j < 16; j++) p += r2[t][j];
        q[g * RR + rq * 16 + t] = p;
    }
}

// ---------------------------------------------------------------------------
// Final: cross attention + gate + clamp, fully wave-parallel.
// k2/v2 are [b][e][r] fp32. Each wave owns 4 g's: scores via per-lane rows
// (4 e per lane), softmax over 256 via 64-lane xor-shuffles, PV via
// shuffle-broadcast of p (coalesced 256B v-row loads). No barriers in g-loop.
// ---------------------------------------------------------------------------
__global__ __launch_bounds__(256) void final_kernel(
    const float* __restrict__ q, const float* __restrict__ k2,
    const float* __restrict__ v2, const float* __restrict__ state,
    const int* __restrict__ tokens, float* __restrict__ out)
{
    const int b = blockIdx.x;
    const int t = threadIdx.x;
    const int w = t >> 6, lane = t & 63;
    __shared__ float qs[GG * RR];
    __shared__ float ctxw[4][RR];

    for (int i = t; i < GG * RR; i += 256) qs[i] = q[i];
    __syncthreads();

    const float* kb = k2 + (size_t)b * EE * RR;
    const float* vb = v2 + (size_t)b * EE * RR;
    float ctxsum = 0.f;                  // lane owns r = lane
#pragma unroll
    for (int gi = 0; gi < 4; ++gi) {
        const int g = w * 4 + gi;
        float sarr[4];
#pragma unroll
        for (int k = 0; k < 4; ++k) {    // e = k*64 + lane
            const float* krow = kb + (size_t)(k * 64 + lane) * RR;
            f32x4 a = {};
#pragma unroll
            for (int r4 = 0; r4 < 16; ++r4) {
                f32x4 kv = *(const f32x4*)(krow + r4 * 4);
                f32x4 qv = *(const f32x4*)(qs + g * RR + r4 * 4);
                a += kv * qv;
            }
            sarr[k] = (a[0] + a[1] + a[2] + a[3]) * 0.125f;
        }
        float mx = fmaxf(fmaxf(sarr[0], sarr[1]), fmaxf(sarr[2], sarr[3]));
#pragma unroll
        for (int off = 32; off; off >>= 1) mx = fmaxf(mx, __shfl_xor(mx, off));
        float ps[4]; float sum = 0.f;
#pragma unroll
        for (int k = 0; k < 4; ++k) { ps[k] = __expf(sarr[k] - mx); sum += ps[k]; }
#pragma unroll
        for (int off = 32; off; off >>= 1) sum += __shfl_xor(sum, off);
        const float inv = 1.0f / sum;
        float c = 0.f;
#pragma unroll
        for (int k = 0; k < 4; ++k) {
            const float pk = ps[k] * inv;
#pragma unroll 8
            for (int e = 0; e < 64; ++e) {
                const float pe = __shfl(pk, e);
                c += pe * vb[(size_t)(k * 64 + e) * RR + lane];
            }
        }
        ctxsum += c;
    }
    ctxw[w][lane] = ctxsum;
    __syncthreads();

    if (w == 0) {
        const float snew = (ctxw[0][lane] + ctxw[1][lane] + ctxw[2][lane] + ctxw[3][lane]) * (1.0f / GG);
        const float prev = state[b * RR + lane];
        float np = prev * prev, ns = snew * snew, dp = prev * snew;
#pragma unroll
        for (int off = 32; off; off >>= 1) {
            np += __shfl_xor(np, off);
            ns += __shfl_xor(ns, off);
            dp += __shfl_xor(dp, off);
        }
        float sim = dp / (fmaxf(sqrtf(np), 1e-6f) * fmaxf(sqrtf(ns), 1e-6f));
        sim = fminf(1.0f, fmaxf(-1.0f, sim));
        float gate = 0.1f + 0.8f * 0.5f * (sim + 1.0f);
        const int tv = tokens[0];
        float tokf = (tv >= 0 && tv < (1 << 24)) ? (float)tv : __int_as_float(tv);
        gate *= fminf(1.0f, tokf * (1.0f / 256.0f));
        const float upd = (1.0f - gate) * prev + gate * snew;
        float nn = upd * upd;
#pragma unroll
        for (int off = 32; off; off >>= 1) nn += __shfl_xor(nn, off);
        const float scale = fminf(1.0f, 10.0f / fmaxf(sqrtf(nn), 1e-6f));
        out[b * RR + lane] = upd * scale;
    }
}

// ---------------------------------------------------------------------------
extern "C" void kernel_launch(void* const* d_in, const int* in_sizes, int n_in,
                              void* d_out, int out_size, void* d_ws, size_t ws_size,
                              hipStream_t stream) {
    const float* state = (const float*)d_in[0];
    const float* ek    = (const float*)d_in[1];
    const float* ev    = (const float*)d_in[2];
    const float* Wq    = (const float*)d_in[3];
    const float* Wk    = (const float*)d_in[4];
    const float* Wv    = (const float*)d_in[5];
    const float* gq    = (const float*)d_in[6];
    const float* lq    = (const float*)d_in[7];
    const int*   tok   = (const int*)d_in[8];
    float* out = (float*)d_out;

    // workspace layout
    const size_t n_part = (size_t)BB * LL * EE * RR;     // 1,048,576
    __hip_bfloat16* kpart = (__hip_bfloat16*)d_ws;        // 2 MB
    __hip_bfloat16* vpart = kpart + n_part;               // 2 MB
    __hip_bfloat16* Bfrag = vpart + n_part;               // 1 MB (2*512*64*8)
    float* fr      = (float*)(Bfrag + (size_t)2 * 512 * 64 * 8);
    float* scores  = fr;                                  // 64
    float* k2      = scores + BB * LL;                    // 128 KB  [b][e][r]
    float* v2      = k2 + (size_t)BB * EE * RR;           // 128 KB
    float* qbuf    = v2 + (size_t)BB * EE * RR;           // 4 KB

    prep_kernel<<<256, 256, 0, stream>>>(Wk, Wv, Bfrag, scores);
    proj_kernel<<<512, 256, 0, stream>>>(ek, ev, Bfrag, lq, kpart, vpart, scores);
    kber_kernel<<<32, 256, 0, stream>>>(kpart, vpart, scores, k2, v2);
    qproj_kernel<<<64, 256, 0, stream>>>(gq, Wq, qbuf);
    final_kernel<<<BB, 256, 0, stream>>>(qbuf, k2, v2, state, tok, out);
}

// Round 2
// 589.159 us; speedup vs baseline: 1.0748x; 1.0458x over previous
//
#include <hip/hip_runtime.h>
#include <hip/hip_bf16.h>
#include <stdint.h>

// Problem dims (fixed)
#define BB 2
#define LL 32
#define EE 256
#define HH 4096
#define GG 16
#define RR 64

typedef __bf16 bf16x8 __attribute__((ext_vector_type(8)));
typedef float f32x4 __attribute__((ext_vector_type(4)));

__device__ inline void async16(const void* g, void* l) {
    __builtin_amdgcn_global_load_lds((const __attribute__((address_space(1))) uint32_t*)g,
                                     (__attribute__((address_space(3))) uint32_t*)l, 16, 0, 0);
}

__device__ inline bf16x8 cvt8(f32x4 a, f32x4 b) {
    bf16x8 r;
    r[0] = (__bf16)a[0]; r[1] = (__bf16)a[1]; r[2] = (__bf16)a[2]; r[3] = (__bf16)a[3];
    r[4] = (__bf16)b[0]; r[5] = (__bf16)b[1]; r[6] = (__bf16)b[2]; r[7] = (__bf16)b[3];
    return r;
}

// ---------------------------------------------------------------------------
// prep_q: blocks 0..255 = prep (Wk/Wv -> frag-native bf16 Bfrag, coalesced
// stores; zero scores). blocks 256..319 = qproj (q[g,r] = sum_h gq*Wq).
// Merged to cut one dispatch; the two halves touch disjoint data.
// ---------------------------------------------------------------------------
__global__ __launch_bounds__(256) void prep_q_kernel(
    const float* __restrict__ Wk, const float* __restrict__ Wv,
    const float* __restrict__ Wq, const float* __restrict__ gq,
    __hip_bfloat16* __restrict__ Bfrag, float* __restrict__ qbuf,
    float* __restrict__ scores)
{
    __shared__ float red[16][256];
    __shared__ float r2[16][17];
    const int blk = blockIdx.x;
    if (blk < 256) {
        // ---- prep ----
        const int tid = blk * 256 + threadIdx.x;   // 65536 tasks
        const int mat = tid >> 15;
        const int kq  = (tid >> 6) & 511;
        const int r   = tid & 63;
        const float* W = mat ? Wv : Wk;
        const float* src = W + (size_t)r * HH + kq * 8;
        f32x4 a = *(const f32x4*)src;
        f32x4 b = *(const f32x4*)(src + 4);
        *(bf16x8*)((__bf16*)Bfrag + (size_t)tid * 8) = cvt8(a, b);   // coalesced
        if (blk == 0 && threadIdx.x < BB * LL) scores[threadIdx.x] = 0.f;
        return;
    }
    // ---- qproj ----
    const int qb = blk - 256;
    const int g  = qb >> 2;
    const int rq = qb & 3;
    const int t  = threadIdx.x;
    float s[16] = {};
    for (int i = 0; i < 4; i++) {
        const int h = i * 1024 + t * 4;
        f32x4 a = *(const f32x4*)(gq + (size_t)g * HH + h);
#pragma unroll
        for (int r = 0; r < 16; r++) {
            f32x4 wv_ = *(const f32x4*)(Wq + (size_t)(rq * 16 + r) * HH + h);
            s[r] += a[0] * wv_[0] + a[1] * wv_[1] + a[2] * wv_[2] + a[3] * wv_[3];
        }
    }
#pragma unroll
    for (int r = 0; r < 16; r++) red[r][t] = s[r];
    __syncthreads();
    {
        const int r = t >> 4, j = t & 15;
        float p = 0.f;
        for (int i = 0; i < 16; i++) p += red[r][j * 16 + i];
        r2[r][j] = p;
    }
    __syncthreads();
    if (t < 16) {
        float p = 0.f;
        for (int j = 0; j < 16; j++) p += r2[t][j];
        qbuf[g * RR + rq * 16 + t] = p;
    }
}

// ---------------------------------------------------------------------------
// Proj: kpart[b,l,e,r] = sum_h K[b,l,e,h]*Wk[r,h]  (vpart with Wv), MFMA.
// Counted-vmcnt async pipeline (T3/T4): k-chunk=32, 3 LDS buffers, stage-ahead 2.
// Per iter each wave issues EXACTLY 4 global_load_lds -> branchless vmcnt(4),
// one raw s_barrier per chunk, vmcnt never drained to 0 in the main loop.
// A is XOR-swizzled on the GLOBAL SOURCE address (linear LDS dest) so the
// ds_read_b128 fragment reads are bank-conflict-free.
// Grid 512 = 64 bl x 8 etiles(32 rows). Waves: (mat, mtile). LDS 48 KB.
// Fused: layer-score partial  sum_{e,r} kout*lq[r]  -> atomicAdd(scores[bl]).
// ---------------------------------------------------------------------------
__global__ __launch_bounds__(256, 4) void proj_kernel(
    const float* __restrict__ ek, const float* __restrict__ ev,
    const __hip_bfloat16* __restrict__ Bfrag, const float* __restrict__ lq,
    __hip_bfloat16* __restrict__ kpart, __hip_bfloat16* __restrict__ vpart,
    float* __restrict__ scores)
{
    __shared__ __align__(16) uint8_t sm[49152];
    uint8_t* smA = sm;
    uint8_t* smB = sm + 24576;

    const int blk  = blockIdx.x;
    const int bl   = blk >> 3;
    const int e0   = (blk & 7) * 32;
    const int t    = threadIdx.x;
    const int w    = t >> 6;
    const int lane = t & 63;
    const int n    = lane & 15;
    const int q    = lane >> 4;
    const int mat  = w >> 1;    // compute role: 0=K 1=V
    const int mt   = w & 1;     // m-tile (rows mt*16..mt*16+15)

    // staging roles: w0 -> A(ek), w1 -> A(ev), w2 -> B-K, w3 -> B-V
    const int row_l = lane >> 3;                       // 0..7
    const int aswz  = ((lane & 7) ^ row_l) << 4;       // source pre-swizzle
    const char* astage = (const char*)((w & 1) ? ev : ek)
        + ((size_t)(bl * EE + e0 + row_l) * HH) * 4 + aswz;
    const char* bstage = (const char*)Bfrag + ((w & 1) ? (size_t)512 * 1024 : (size_t)0)
        + (size_t)lane * 16;
    uint8_t* adst0 = smA + (w & 1) * 4096;
    uint8_t* bdst0 = smB + (w & 1) * 4096;
    const bool isA = (w < 2);

    auto stage = [&](int cc, int sb) {
        if (isA) {
            const char* g = astage + (size_t)cc * 128;
            uint8_t* d = adst0 + sb * 8192;
#pragma unroll
            for (int p = 0; p < 4; ++p)                 // rows p*8..p*8+7
                async16(g + (size_t)p * (8 * HH * 4), d + p * 1024);
        } else {
            const char* g = bstage + (size_t)cc * 4096;
            uint8_t* d = bdst0 + sb * 8192;
#pragma unroll
            for (int i = 0; i < 4; ++i)                 // kq = cc*4 + i
                async16(g + i * 1024, d + i * 1024);
        }
    };

    f32x4 acc[4] = {};
    const int m = mt * 16 + n;
    const uint8_t* arow0 = smA + mat * 4096 + m * 128;
    const int sA0 = ((2 * q) ^ (n & 7)) << 4;           // swizzled 16B slots
    const int sA1 = ((2 * q + 1) ^ (n & 7)) << 4;
    const uint8_t* brow0 = smB + mat * 4096 + q * 1024 + n * 16;

    stage(0, 0);
    stage(1, 1);

    int cb = 0;                                         // cb = c % 3
    for (int c = 0; c < 128; ++c) {
        asm volatile("s_waitcnt vmcnt(4)" ::: "memory");
        __builtin_amdgcn_s_barrier();
        asm volatile("" ::: "memory");

        stage((c + 2) & 127, cb >= 1 ? cb - 1 : 2);     // buf (c+2)%3

        const uint8_t* arow = arow0 + cb * 8192;
        f32x4 a0 = *(const f32x4*)(arow + sA0);
        f32x4 a1 = *(const f32x4*)(arow + sA1);
        bf16x8 af = cvt8(a0, a1);
        const uint8_t* brow = brow0 + cb * 8192;
#pragma unroll
        for (int nt = 0; nt < 4; ++nt) {
            bf16x8 bv = *(const bf16x8*)(brow + nt * 256);
            acc[nt] = __builtin_amdgcn_mfma_f32_16x16x32_bf16(af, bv, acc[nt], 0, 0, 0);
        }
        asm volatile("" ::: "memory");
        cb = (cb == 2) ? 0 : cb + 1;
    }

    __hip_bfloat16* outp = (mat == 0) ? kpart : vpart;
    float lqv[4];
    if (mat == 0) {
#pragma unroll
        for (int nt = 0; nt < 4; ++nt) lqv[nt] = lq[nt * 16 + n];
    }
    float sc = 0.f;
#pragma unroll
    for (int nt = 0; nt < 4; ++nt)
#pragma unroll
        for (int reg = 0; reg < 4; ++reg) {
            const int e_row = e0 + mt * 16 + q * 4 + reg;
            outp[((size_t)bl * EE + e_row) * RR + nt * 16 + n] = __float2bfloat16(acc[nt][reg]);
            if (mat == 0) sc += acc[nt][reg] * lqv[nt];
        }
    if (mat == 0) {
#pragma unroll
        for (int off = 32; off > 0; off >>= 1) sc += __shfl_down(sc, off, 64);
        if (lane == 0) atomicAdd(&scores[bl], sc);
    }
    asm volatile("s_waitcnt vmcnt(0)" ::: "memory");    // drain tail stages
}

// ---------------------------------------------------------------------------
// tail: kber + final fused. Grid 2 (one block per b), 256 threads.
// Phase 1: softmax(scores) per wave via shuffles.
// Phase 2: k2/v2 = sum_l w_l * {k,v}part  -> LDS (fp32, padded strides:
//          k2 stride 68 words (16B-aligned rows, b128 reads uniform 8/bank),
//          v2 stride 65 (scalar access, 2-way max)). Coalesced 1KB/wave loads.
// Phase 3: cross-attn fully from LDS. Wave w owns g = 4w..4w+3; lane owns
//          e=lane+64k for scores (per-lane full 64-dot, no shuffles) and
//          r=lane for PV (p broadcast from LDS). No block barriers in g-loop.
// Phase 4: gate + norm clamp on wave 0.
// ---------------------------------------------------------------------------
#define K2S 68
#define V2S 65
__global__ __launch_bounds__(256) void tail_kernel(
    const __hip_bfloat16* __restrict__ kpart, const __hip_bfloat16* __restrict__ vpart,
    const float* __restrict__ scores, const float* __restrict__ q,
    const float* __restrict__ state, const int* __restrict__ tokens,
    float* __restrict__ out)
{
    __shared__ float k2[EE][K2S];      // 69632 B
    __shared__ float v2[EE][V2S];      // 66560 B
    __shared__ float qs[GG * RR];      // 4 KB
    __shared__ float pw[4][EE];        // 4 KB
    __shared__ float ctxw[4][RR];

    const int b = blockIdx.x;
    const int t = threadIdx.x;
    const int w = t >> 6, lane = t & 63;

    // Phase 1: softmax weights (per-wave, lanes 32-63 mirror 0-31)
    float sv = scores[b * LL + (lane & 31)] * (1.f / 2048.f);
    float mx = sv;
#pragma unroll
    for (int off = 16; off; off >>= 1) mx = fmaxf(mx, __shfl_xor(mx, off));
    float ex = __expf(sv - mx), sum = ex;
#pragma unroll
    for (int off = 16; off; off >>= 1) sum += __shfl_xor(sum, off);
    const float wgt = ex / sum;                     // lane holds w_l, l=lane&31

    for (int i = t; i < GG * RR; i += 256) qs[i] = q[i];

    // Phase 2: weighted reduce into LDS. thread -> (r8 = t&7, e = (t>>3)+32*es)
    const int r8 = t & 7;
    const int eb = t >> 3;
#pragma unroll
    for (int es = 0; es < 8; ++es) {
        const int e = eb + 32 * es;
        float ak[8] = {}, av[8] = {};
        const __bf16* kb = (const __bf16*)kpart + ((size_t)(b * LL) * EE + e) * RR + r8 * 8;
        const __bf16* vb = (const __bf16*)vpart + ((size_t)(b * LL) * EE + e) * RR + r8 * 8;
#pragma unroll 4
        for (int l = 0; l < LL; ++l) {
            const float wl = __shfl(wgt, l);
            bf16x8 k8 = *(const bf16x8*)(kb + (size_t)l * EE * RR);
            bf16x8 v8 = *(const bf16x8*)(vb + (size_t)l * EE * RR);
#pragma unroll
            for (int j = 0; j < 8; ++j) { ak[j] += wl * (float)k8[j]; av[j] += wl * (float)v8[j]; }
        }
#pragma unroll
        for (int j = 0; j < 8; ++j) {
            k2[e][r8 * 8 + j] = ak[j];
            v2[e][r8 * 8 + j] = av[j];
        }
    }
    __syncthreads();

    // Phase 3: attention, all from LDS
    float ctxsum = 0.f;                             // lane owns r = lane in PV
#pragma unroll
    for (int gi = 0; gi < 4; ++gi) {
        const int g = w * 4 + gi;
        float sarr[4];
#pragma unroll
        for (int k = 0; k < 4; ++k) {               // e = k*64 + lane
            const int e = k * 64 + lane;
            f32x4 a = {};
#pragma unroll
            for (int r4 = 0; r4 < 16; ++r4) {
                f32x4 kv = *(const f32x4*)(&k2[e][r4 * 4]);
                f32x4 qv = *(const f32x4*)(qs + g * RR + r4 * 4);
                a += kv * qv;
            }
            sarr[k] = (a[0] + a[1] + a[2] + a[3]) * 0.125f;
        }
        float mg = fmaxf(fmaxf(sarr[0], sarr[1]), fmaxf(sarr[2], sarr[3]));
#pragma unroll
        for (int off = 32; off; off >>= 1) mg = fmaxf(mg, __shfl_xor(mg, off));
        float ps[4]; float sg = 0.f;
#pragma unroll
        for (int k = 0; k < 4; ++k) { ps[k] = __expf(sarr[k] - mg); sg += ps[k]; }
#pragma unroll
        for (int off = 32; off; off >>= 1) sg += __shfl_xor(sg, off);
        const float inv = 1.0f / sg;
#pragma unroll
        for (int k = 0; k < 4; ++k) pw[w][k * 64 + lane] = ps[k] * inv;
        // PV: c = sum_e pw[e] * v2[e][lane]
        float c = 0.f;
#pragma unroll 8
        for (int e = 0; e < EE; ++e) c += pw[w][e] * v2[e][lane];
        ctxsum += c;
    }
    ctxw[w][lane] = ctxsum;
    __syncthreads();

    // Phase 4: gate + clamp
    if (w == 0) {
        const float snew = (ctxw[0][lane] + ctxw[1][lane] + ctxw[2][lane] + ctxw[3][lane]) * (1.0f / GG);
        const float prev = state[b * RR + lane];
        float np = prev * prev, ns = snew * snew, dp = prev * snew;
#pragma unroll
        for (int off = 32; off; off >>= 1) {
            np += __shfl_xor(np, off);
            ns += __shfl_xor(ns, off);
            dp += __shfl_xor(dp, off);
        }
        float sim = dp / (fmaxf(sqrtf(np), 1e-6f) * fmaxf(sqrtf(ns), 1e-6f));
        sim = fminf(1.0f, fmaxf(-1.0f, sim));
        float gate = 0.1f + 0.8f * 0.5f * (sim + 1.0f);
        const int tv = tokens[0];
        float tokf = (tv >= 0 && tv < (1 << 24)) ? (float)tv : __int_as_float(tv);
        gate *= fminf(1.0f, tokf * (1.0f / 256.0f));
        const float upd = (1.0f - gate) * prev + gate * snew;
        float nn = upd * upd;
#pragma unroll
        for (int off = 32; off; off >>= 1) nn += __shfl_xor(nn, off);
        const float scale = fminf(1.0f, 10.0f / fmaxf(sqrtf(nn), 1e-6f));
        out[b * RR + lane] = upd * scale;
    }
}

// ---------------------------------------------------------------------------
extern "C" void kernel_launch(void* const* d_in, const int* in_sizes, int n_in,
                              void* d_out, int out_size, void* d_ws, size_t ws_size,
                              hipStream_t stream) {
    const float* state = (const float*)d_in[0];
    const float* ek    = (const float*)d_in[1];
    const float* ev    = (const float*)d_in[2];
    const float* Wq    = (const float*)d_in[3];
    const float* Wk    = (const float*)d_in[4];
    const float* Wv    = (const float*)d_in[5];
    const float* gq    = (const float*)d_in[6];
    const float* lq    = (const float*)d_in[7];
    const int*   tok   = (const int*)d_in[8];
    float* out = (float*)d_out;

    const size_t n_part = (size_t)BB * LL * EE * RR;      // 1,048,576
    __hip_bfloat16* kpart = (__hip_bfloat16*)d_ws;        // 2 MB
    __hip_bfloat16* vpart = kpart + n_part;               // 2 MB
    __hip_bfloat16* Bfrag = vpart + n_part;               // 1 MB
    float* fr      = (float*)(Bfrag + (size_t)2 * 512 * 64 * 8);
    float* scores  = fr;                                  // 256 B
    float* qbuf    = scores + BB * LL;                    // 4 KB

    prep_q_kernel<<<320, 256, 0, stream>>>(Wk, Wv, Wq, gq, Bfrag, qbuf, scores);
    proj_kernel<<<512, 256, 0, stream>>>(ek, ev, Bfrag, lq, kpart, vpart, scores);
    tail_kernel<<<BB, 256, 0, stream>>>(kpart, vpart, scores, qbuf, state, tok, out);
}